// Round 12
// baseline (798.658 us; speedup 1.0000x reference)
//
#include <hip/hip_runtime.h>

#define NUMS   128
#define NVARS  16
#define BATCH  8192
#define ITERS  15

// d_out element offsets (return order: cv, cp, cr, acc_fixed, acc_primal, primal_stack, fixed_stack)
#define OUT_ACCF (3*BATCH*NVARS)           // 393216
#define OUT_ACCP (OUT_ACCF + BATCH)        // 401408
#define OUT_PST  (OUT_ACCP + BATCH)        // 409600
#define OUT_FST  (OUT_PST + ITERS*BATCH)   // 532480

// ---------------------------------------------------------------------------
// prep: AtA = 2(P^T P + Pd^T Pd + Pdd^T Pdd); cost_mat = [[I+AtA, Aeq^T],[Aeq,0]];
// M = inv(cost_mat) via f64 Gauss-Jordan. ws: [0,324) M row-major f32,
// [324,596) AtA padded [16][17] f32.
// ---------------------------------------------------------------------------
__global__ void prep_kernel(const float* __restrict__ P, const float* __restrict__ Pd,
                            const float* __restrict__ Pdd, float* __restrict__ ws)
{
    __shared__ double GA[18][36];
    __shared__ float  ata[16][16];
    __shared__ double piv_s;
    const int t = threadIdx.x;

    if (t < 256) {
        int j = t >> 4, k = t & 15;
        float s = 0.f;
        for (int i = 0; i < NUMS; ++i)
            s += P[i*16+j]*P[i*16+k] + Pd[i*16+j]*Pd[i*16+k] + Pdd[i*16+j]*Pdd[i*16+k];
        ata[j][k] = 2.f * s;
    }
    __syncthreads();

    const int gi = t / 36, gj = t % 36;   // blockDim = 648
    {
        double v;
        if (gj < 18) {
            if (gi < 16 && gj < 16)      v = (gi == gj ? 1.0 : 0.0) + (double)ata[gi][gj];
            else if (gi < 16)            v = (gj == 16) ? (double)P[gi] : (double)Pd[gi];
            else if (gj < 16)            v = (gi == 16) ? (double)P[gj] : (double)Pd[gj];
            else                         v = 0.0;
        } else {
            v = ((gj - 18) == gi) ? 1.0 : 0.0;
        }
        GA[gi][gj] = v;
    }
    __syncthreads();

    for (int k = 0; k < 18; ++k) {
        if (t == 0) piv_s = GA[k][k];
        __syncthreads();
        if (gi == k) GA[gi][gj] /= piv_s;
        __syncthreads();
        double f  = GA[gi][k];
        double rk = GA[k][gj];
        __syncthreads();
        if (gi != k) GA[gi][gj] -= f * rk;
        __syncthreads();
    }

    if (gj >= 18) ws[gi*18 + (gj - 18)] = (float)GA[gi][gj];
    if (t < 256)  ws[324 + (t >> 4)*17 + (t & 15)] = ata[t >> 4][t & 15];
    if (t >= 256 && t < 272) ws[324 + (t - 256)*17 + 16] = 0.f;
}

// reduce-scatter of a 16-vector across 16 lanes: lane l returns sum_j of its
// own component j=l. 4 halving stages, static indexing (verified R11).
__device__ __forceinline__ float reduce_scatter16(const float (&pjp)[16], int l)
{
    float v8[8];
#pragma unroll
    for (int k = 0; k < 8; ++k) {
        float send = (l & 8) ? pjp[k] : pjp[k+8];
        float keep = (l & 8) ? pjp[k+8] : pjp[k];
        v8[k] = keep + __shfl_xor(send, 8, 16);
    }
    float v4[4];
#pragma unroll
    for (int k = 0; k < 4; ++k) {
        float send = (l & 4) ? v8[k] : v8[k+4];
        float keep = (l & 4) ? v8[k+4] : v8[k];
        v4[k] = keep + __shfl_xor(send, 4, 16);
    }
    float v2[2];
#pragma unroll
    for (int k = 0; k < 2; ++k) {
        float send = (l & 2) ? v4[k] : v4[k+2];
        float keep = (l & 2) ? v4[k+2] : v4[k];
        v2[k] = keep + __shfl_xor(send, 2, 16);
    }
    float send = (l & 1) ? v2[0] : v2[1];
    float keep = (l & 1) ? v2[1] : v2[0];
    return keep + __shfl_xor(send, 1, 16);
}

// ---------------------------------------------------------------------------
// main solver: block = 192 threads = 12 groups of 16 lanes; each group handles
// TWO batch rows of one channel (block = 8 rows x 3 channels). R11 was
// LDS-pipe-bound (192 ds_read_b128/wave/iter vs ~1250 VALU); sharing every Pt
// read between the 2 rows halves LDS instructions per row (one read feeds
// unA/unB and pjpA/pjpB FMA pairs). Grid halves to 1024.
// cs padded [2][17] + group stride 34 so the 4 groups of a wave hit distinct
// banks (2g apart) on the scalar c-broadcast reads.
// ---------------------------------------------------------------------------
__launch_bounds__(192, 1)
__global__ void solve_kernel(
    const float* __restrict__ P,    const float* __restrict__ Pd,   const float* __restrict__ Pdd,
    const float* __restrict__ lamv, const float* __restrict__ lamp, const float* __restrict__ lamr,
    const float* __restrict__ cinv, const float* __restrict__ cinp, const float* __restrict__ cinr,
    const float* __restrict__ beqv, const float* __restrict__ beqp, const float* __restrict__ beqr,
    const float* __restrict__ c0v,  const float* __restrict__ c0p,  const float* __restrict__ c0r,
    float* __restrict__ out, const float* __restrict__ ws)
{
    __shared__ __align__(16) float Pt[3][16][128];   // transposed: Pt[m][j][i]
    __shared__ float Ml[16][19];                     // M rows 0..15, cols 0..17 (pad 19)
    __shared__ float ata[16][17];
    __shared__ float cs[12][2][17];                  // per-group c, 2 rows, padded
    __shared__ float res_st[ITERS][24];
    __shared__ float fix_st[ITERS][24];

    // ---- stage constants ----
#pragma unroll
    for (int m = 0; m < 3; ++m) {
        const float* src = (m == 0) ? P : (m == 1) ? Pd : Pdd;
        for (int f = threadIdx.x; f < 2048; f += 192) {
            int j = f >> 7, i = f & 127;
            Pt[m][j][i] = src[i*16 + j];
        }
    }
    for (int f = threadIdx.x; f < 288; f += 192) Ml[f / 18][f % 18] = ws[f];
    for (int f = threadIdx.x; f < 272; f += 192) ata[f / 17][f % 17] = ws[324 + f];
    __syncthreads();

    const int g  = threadIdx.x >> 4;   // group 0..11
    const int l  = threadIdx.x & 15;   // lane-in-group
    const int rl = g / 3;              // local row-pair 0..3
    const int ch = g - rl * 3;         // channel 0..2
    const int rowA = blockIdx.x * 8 + rl * 2;
    const int rowB = rowA + 1;

    const float* lam_p = (ch == 0) ? lamv : (ch == 1) ? lamp : lamr;
    const float* cin_p = (ch == 0) ? cinv : (ch == 1) ? cinp : cinr;
    const float* beq_p = (ch == 0) ? beqv : (ch == 1) ? beqp : beqr;
    const float* c0_p  = (ch == 0) ? c0v  : (ch == 1) ? c0p  : c0r;

    // bounds per (ch, m)
    float bmax[3], bmin[3];
    bmax[0] = (ch == 0) ? 20.f : (ch == 1) ? 0.2f  : 0.25f;
    bmin[0] = (ch == 0) ? 12.f : (ch == 1) ? -0.2f : -0.25f;
    bmax[1] = (ch == 0) ? 3.f  : 0.25f;
    bmin[1] = (ch == 0) ? -3.f : -0.25f;
    bmax[2] = (ch == 0) ? 3.f  : 0.15f;
    bmin[2] = (ch == 0) ? -3.f : -0.15f;

    // ---- distributed per-unit state: lane l owns component l, 2 rows ----
    float cA = c0_p[rowA * 16 + l];
    float cB = c0_p[rowB * 16 + l];
    float LA = lam_p[rowA * 16 + l] + cin_p[rowA * 16 + l];
    float LB = lam_p[rowB * 16 + l] + cin_p[rowB * 16 + l];
    float pjA, pjB, cqA, cqB;
    const float beqA0 = beq_p[rowA * 2], beqA1 = beq_p[rowA * 2 + 1];
    const float beqB0 = beq_p[rowB * 2], beqB1 = beq_p[rowB * 2 + 1];
    float uoA[3][8], uoB[3][8];

    cs[g][0][l] = cA;
    cs[g][1][l] = cB;

    // ---- init pass ----
    {
        float pjpA[16], pjpB[16];
#pragma unroll
        for (int j = 0; j < 16; ++j) { pjpA[j] = 0.f; pjpB[j] = 0.f; }

#pragma unroll
        for (int m = 0; m < 3; ++m) {
            float unA[8], unB[8];
#pragma unroll
            for (int k = 0; k < 8; ++k) { unA[k] = 0.f; unB[k] = 0.f; }
#pragma unroll 4
            for (int j = 0; j < 16; ++j) {
                float cjA = cs[g][0][j];
                float cjB = cs[g][1][j];
                float4 p0 = *(const float4*)&Pt[m][j][4*l];
                float4 p1 = *(const float4*)&Pt[m][j][64 + 4*l];
                unA[0] += cjA*p0.x; unA[1] += cjA*p0.y; unA[2] += cjA*p0.z; unA[3] += cjA*p0.w;
                unA[4] += cjA*p1.x; unA[5] += cjA*p1.y; unA[6] += cjA*p1.z; unA[7] += cjA*p1.w;
                unB[0] += cjB*p0.x; unB[1] += cjB*p0.y; unB[2] += cjB*p0.z; unB[3] += cjB*p0.w;
                unB[4] += cjB*p1.x; unB[5] += cjB*p1.y; unB[6] += cjB*p1.z; unB[7] += cjB*p1.w;
            }
            float hA[8], hB[8];
#pragma unroll
            for (int k = 0; k < 8; ++k) {
                float xA = unA[k] - bmax[m];
                float yA = unA[k] - bmin[m];
                hA[k] = fmaxf(xA, 0.f) - fmaxf(-yA, 0.f);
                uoA[m][k] = unA[k];
                float xB = unB[k] - bmax[m];
                float yB = unB[k] - bmin[m];
                hB[k] = fmaxf(xB, 0.f) - fmaxf(-yB, 0.f);
                uoB[m][k] = unB[k];
            }
#pragma unroll 4
            for (int j = 0; j < 16; ++j) {
                float4 p0 = *(const float4*)&Pt[m][j][4*l];
                float4 p1 = *(const float4*)&Pt[m][j][64 + 4*l];
                pjpA[j] += hA[0]*p0.x + hA[1]*p0.y + hA[2]*p0.z + hA[3]*p0.w
                         + hA[4]*p1.x + hA[5]*p1.y + hA[6]*p1.z + hA[7]*p1.w;
                pjpB[j] += hB[0]*p0.x + hB[1]*p0.y + hB[2]*p0.z + hB[3]*p0.w
                         + hB[4]*p1.x + hB[5]*p1.y + hB[6]*p1.z + hB[7]*p1.w;
            }
        }
        pjA = reduce_scatter16(pjpA, l);
        pjB = reduce_scatter16(pjpB, l);

        float cqa = 0.f, cqb = 0.f;
#pragma unroll
        for (int k = 0; k < 16; ++k) {
            float av = ata[l][k];
            cqa += av * cs[g][0][k];
            cqb += av * cs[g][1][k];
        }
        cqA = cqa; cqB = cqb;
    }

    // ---- 15 ADMM iterations ----
    for (int t = 0; t < ITERS; ++t) {
        // KKT solve, both rows share Ml reads
        float rA = LA + cqA - pjA;
        float rB = LB + cqB - pjB;
        float sjA = Ml[l][16] * beqA0 + Ml[l][17] * beqA1;
        float sjB = Ml[l][16] * beqB0 + Ml[l][17] * beqB1;
#pragma unroll
        for (int k = 0; k < 16; ++k) {
            float mk = Ml[l][k];
            sjA += mk * __shfl(rA, k, 16);
            sjB += mk * __shfl(rB, k, 16);
        }
        float dA = sjA - cA, dB = sjB - cB;
        float cdel2A = dA * dA, cdel2B = dB * dB;
        cA = sjA; cB = sjB;
        cs[g][0][l] = cA;
        cs[g][1][l] = cB;

        // fused Ax + projection + pjp accumulation, Pt reads shared by 2 rows
        float res2A = 0.f, ds2A = 0.f, res2B = 0.f, ds2B = 0.f;
        float pjpA[16], pjpB[16];
#pragma unroll
        for (int j = 0; j < 16; ++j) { pjpA[j] = 0.f; pjpB[j] = 0.f; }

#pragma unroll
        for (int m = 0; m < 3; ++m) {
            float unA[8], unB[8];
#pragma unroll
            for (int k = 0; k < 8; ++k) { unA[k] = 0.f; unB[k] = 0.f; }
#pragma unroll 4
            for (int j = 0; j < 16; ++j) {
                float cjA = cs[g][0][j];
                float cjB = cs[g][1][j];
                float4 p0 = *(const float4*)&Pt[m][j][4*l];
                float4 p1 = *(const float4*)&Pt[m][j][64 + 4*l];
                unA[0] += cjA*p0.x; unA[1] += cjA*p0.y; unA[2] += cjA*p0.z; unA[3] += cjA*p0.w;
                unA[4] += cjA*p1.x; unA[5] += cjA*p1.y; unA[6] += cjA*p1.z; unA[7] += cjA*p1.w;
                unB[0] += cjB*p0.x; unB[1] += cjB*p0.y; unB[2] += cjB*p0.z; unB[3] += cjB*p0.w;
                unB[4] += cjB*p1.x; unB[5] += cjB*p1.y; unB[6] += cjB*p1.z; unB[7] += cjB*p1.w;
            }
            float hA[8], hB[8];
#pragma unroll
            for (int k = 0; k < 8; ++k) {
                {
                    float x   = unA[k] - bmax[m];
                    float rvp = fmaxf(x, 0.f);
                    float spn = rvp - x;
                    float y   = unA[k] - bmin[m];
                    float smn = fmaxf(y, 0.f);
                    float rvm = smn - y;
                    res2A += rvp * rvp + rvm * rvm;
                    hA[k] = rvp - rvm;
                    float xo  = uoA[m][k] - bmax[m];
                    float spo = fmaxf(-xo, 0.f);
                    float yo  = uoA[m][k] - bmin[m];
                    float smo = fmaxf(yo, 0.f);
                    float e1 = spn - spo, e2 = smn - smo;
                    ds2A += e1 * e1 + e2 * e2;
                    uoA[m][k] = unA[k];
                }
                {
                    float x   = unB[k] - bmax[m];
                    float rvp = fmaxf(x, 0.f);
                    float spn = rvp - x;
                    float y   = unB[k] - bmin[m];
                    float smn = fmaxf(y, 0.f);
                    float rvm = smn - y;
                    res2B += rvp * rvp + rvm * rvm;
                    hB[k] = rvp - rvm;
                    float xo  = uoB[m][k] - bmax[m];
                    float spo = fmaxf(-xo, 0.f);
                    float yo  = uoB[m][k] - bmin[m];
                    float smo = fmaxf(yo, 0.f);
                    float e1 = spn - spo, e2 = smn - smo;
                    ds2B += e1 * e1 + e2 * e2;
                    uoB[m][k] = unB[k];
                }
            }
#pragma unroll 4
            for (int j = 0; j < 16; ++j) {
                float4 p0 = *(const float4*)&Pt[m][j][4*l];
                float4 p1 = *(const float4*)&Pt[m][j][64 + 4*l];
                pjpA[j] += hA[0]*p0.x + hA[1]*p0.y + hA[2]*p0.z + hA[3]*p0.w
                         + hA[4]*p1.x + hA[5]*p1.y + hA[6]*p1.z + hA[7]*p1.w;
                pjpB[j] += hB[0]*p0.x + hB[1]*p0.y + hB[2]*p0.z + hB[3]*p0.w
                         + hB[4]*p1.x + hB[5]*p1.y + hB[6]*p1.z + hB[7]*p1.w;
            }
        }

        pjA = reduce_scatter16(pjpA, l);
        pjB = reduce_scatter16(pjpB, l);

        // cq for next solve (shared ata reads)
        float cqa = 0.f, cqb = 0.f;
#pragma unroll
        for (int k = 0; k < 16; ++k) {
            float av = ata[l][k];
            cqa += av * cs[g][0][k];
            cqb += av * cs[g][1][k];
        }
        cqA = cqa; cqB = cqb;

        // butterfly 8 scalars across the 16 lanes
        float pj2A = pjA * pjA, pj2B = pjB * pjB;
#pragma unroll
        for (int s = 1; s < 16; s <<= 1) {
            res2A  += __shfl_xor(res2A,  s, 16);
            ds2A   += __shfl_xor(ds2A,   s, 16);
            cdel2A += __shfl_xor(cdel2A, s, 16);
            pj2A   += __shfl_xor(pj2A,   s, 16);
            res2B  += __shfl_xor(res2B,  s, 16);
            ds2B   += __shfl_xor(ds2B,   s, 16);
            cdel2B += __shfl_xor(cdel2B, s, 16);
            pj2B   += __shfl_xor(pj2B,   s, 16);
        }

        LA -= pjA;
        LB -= pjB;

        if (l == 0) {
            int ua = (rl * 2) * 3 + ch;
            int ub = (rl * 2 + 1) * 3 + ch;
            res_st[t][ua] = sqrtf(res2A);
            res_st[t][ub] = sqrtf(res2B);
            fix_st[t][ua] = sqrtf(pj2A) + sqrtf(ds2A) + sqrtf(cdel2A);
            fix_st[t][ub] = sqrtf(pj2B) + sqrtf(ds2B) + sqrtf(cdel2B);
        }
    }

    // ---- outputs ----
    out[ch * (BATCH * NVARS) + rowA * 16 + l] = cA;
    out[ch * (BATCH * NVARS) + rowB * 16 + l] = cB;

    __syncthreads();
    const int t2 = threadIdx.x;
    for (int f = t2; f < 240; f += 192) {
        int which = f / 120;           // 0 = primal_stack, 1 = fixed_stack
        int idx = f - which * 120;
        int it = idx % 15, r2 = idx / 15, gb = r2 * 3;
        const float (*st)[24] = which ? fix_st : res_st;
        float v = st[it][gb] + st[it][gb + 1] + st[it][gb + 2];
        out[(which ? OUT_FST : OUT_PST) + it * BATCH + blockIdx.x * 8 + r2] = v;
    }
    if (t2 < 8) {
        int gb = t2 * 3;
        float s = 0.f;
        for (int it = 0; it < ITERS; ++it)
            s += fix_st[it][gb] + fix_st[it][gb + 1] + fix_st[it][gb + 2];
        out[OUT_ACCF + blockIdx.x * 8 + t2] = s * (1.f / 15.f);
    } else if (t2 < 16) {
        int r2 = t2 - 8, gb = r2 * 3;
        float s = 0.f;
        for (int it = 0; it < ITERS; ++it)
            s += res_st[it][gb] + res_st[it][gb + 1] + res_st[it][gb + 2];
        out[OUT_ACCP + blockIdx.x * 8 + r2] = s * (1.f / 15.f);
    }
}

extern "C" void kernel_launch(void* const* d_in, const int* in_sizes, int n_in,
                              void* d_out, int out_size, void* d_ws, size_t ws_size,
                              hipStream_t stream)
{
    const float* P    = (const float*)d_in[0];
    const float* Pdm  = (const float*)d_in[1];
    const float* Pddm = (const float*)d_in[2];
    const float* lamv = (const float*)d_in[3];
    const float* lamp = (const float*)d_in[4];
    const float* lamr = (const float*)d_in[5];
    const float* cinv = (const float*)d_in[6];
    const float* cinp = (const float*)d_in[7];
    const float* cinr = (const float*)d_in[8];
    const float* beqv = (const float*)d_in[9];
    const float* beqp = (const float*)d_in[10];
    const float* beqr = (const float*)d_in[11];
    const float* c0v  = (const float*)d_in[12];
    const float* c0p  = (const float*)d_in[13];
    const float* c0r  = (const float*)d_in[14];
    float* ws = (float*)d_ws;

    prep_kernel<<<1, 648, 0, stream>>>(P, Pdm, Pddm, ws);
    solve_kernel<<<1024, 192, 0, stream>>>(P, Pdm, Pddm,
        lamv, lamp, lamr, cinv, cinp, cinr,
        beqv, beqp, beqr, c0v, c0p, c0r,
        (float*)d_out, ws);
}

// Round 13
// 508.145 us; speedup vs baseline: 1.5717x; 1.5717x over previous
//
#include <hip/hip_runtime.h>

#define NUMS   128
#define NVARS  16
#define BATCH  8192
#define ITERS  15

// d_out element offsets (return order: cv, cp, cr, acc_fixed, acc_primal, primal_stack, fixed_stack)
#define OUT_ACCF (3*BATCH*NVARS)           // 393216
#define OUT_ACCP (OUT_ACCF + BATCH)        // 401408
#define OUT_PST  (OUT_ACCP + BATCH)        // 409600
#define OUT_FST  (OUT_PST + ITERS*BATCH)   // 532480

// ---------------------------------------------------------------------------
// prep: Q = 2(P^T P + Pd^T Pd + Pdd^T Pdd); cost_mat = [[I+Q, Aeq^T],[Aeq,0]];
// M = inv(cost_mat) via f64 Gauss-Jordan. ws layout:
//   [0,324)      M rows 0..17 x cols 0..17 (f32, only rows 0..15 used)
//   [324,596)    MQ = M(0:16,0:16) x Q, padded [16][17] (f32)
// ---------------------------------------------------------------------------
__global__ void prep_kernel(const float* __restrict__ P, const float* __restrict__ Pd,
                            const float* __restrict__ Pdd, float* __restrict__ ws)
{
    __shared__ double GA[18][36];
    __shared__ float  ata[16][16];
    __shared__ double piv_s;
    const int t = threadIdx.x;

    if (t < 256) {
        int j = t >> 4, k = t & 15;
        float s = 0.f;
        for (int i = 0; i < NUMS; ++i)
            s += P[i*16+j]*P[i*16+k] + Pd[i*16+j]*Pd[i*16+k] + Pdd[i*16+j]*Pdd[i*16+k];
        ata[j][k] = 2.f * s;
    }
    __syncthreads();

    const int gi = t / 36, gj = t % 36;   // blockDim = 648
    {
        double v;
        if (gj < 18) {
            if (gi < 16 && gj < 16)      v = (gi == gj ? 1.0 : 0.0) + (double)ata[gi][gj];
            else if (gi < 16)            v = (gj == 16) ? (double)P[gi] : (double)Pd[gi];
            else if (gj < 16)            v = (gi == 16) ? (double)P[gj] : (double)Pd[gj];
            else                         v = 0.0;
        } else {
            v = ((gj - 18) == gi) ? 1.0 : 0.0;
        }
        GA[gi][gj] = v;
    }
    __syncthreads();

    for (int k = 0; k < 18; ++k) {
        if (t == 0) piv_s = GA[k][k];
        __syncthreads();
        if (gi == k) GA[gi][gj] /= piv_s;
        __syncthreads();
        double f  = GA[gi][k];
        double rk = GA[k][gj];
        __syncthreads();
        if (gi != k) GA[gi][gj] -= f * rk;
        __syncthreads();
    }

    // M is in GA[:, 18:36]
    if (gj >= 18) ws[gi*18 + (gj - 18)] = (float)GA[gi][gj];

    // MQ[j][k] = sum_i M[j][i] * Q[i][k]  (f64 accumulate)
    if (t < 256) {
        int j = t >> 4, k = t & 15;
        double s = 0.0;
        for (int i = 0; i < 16; ++i)
            s += GA[j][18 + i] * (double)ata[i][k];
        ws[324 + j*17 + k] = (float)s;
    }
    if (t >= 256 && t < 272) ws[324 + (t - 256)*17 + 16] = 0.f;
}

// reduce-scatter of a 16-vector across 16 lanes: lane l returns sum over lanes
// of component l. 4 halving stages, static indexing (verified R11).
__device__ __forceinline__ float reduce_scatter16(const float (&pjp)[16], int l)
{
    float v8[8];
#pragma unroll
    for (int k = 0; k < 8; ++k) {
        float send = (l & 8) ? pjp[k] : pjp[k+8];
        float keep = (l & 8) ? pjp[k+8] : pjp[k];
        v8[k] = keep + __shfl_xor(send, 8, 16);
    }
    float v4[4];
#pragma unroll
    for (int k = 0; k < 4; ++k) {
        float send = (l & 4) ? v8[k] : v8[k+4];
        float keep = (l & 4) ? v8[k+4] : v8[k];
        v4[k] = keep + __shfl_xor(send, 4, 16);
    }
    float v2[2];
#pragma unroll
    for (int k = 0; k < 2; ++k) {
        float send = (l & 2) ? v4[k] : v4[k+2];
        float keep = (l & 2) ? v4[k+2] : v4[k];
        v2[k] = keep + __shfl_xor(send, 2, 16);
    }
    float send = (l & 1) ? v2[0] : v2[1];
    float keep = (l & 1) ? v2[1] : v2[0];
    return keep + __shfl_xor(send, 1, 16);
}

// ---------------------------------------------------------------------------
// main solver: block = 192 threads = 12 groups of 16 lanes = 4 rows x 3 ch.
// R11 structure (455us, ~90% DS-pipe-saturated; R12's 2-row variant regressed
// to 824us via VGPR 232 -> 2 waves/SIMD). One refinement vs R11: cq = Q*c is
// folded into the KKT solve via precomputed MQ = M*Q (prep, f64) — removes
// the separate cq stage; KKT reads old cs BEFORE overwriting.
// ---------------------------------------------------------------------------
__launch_bounds__(192, 1)
__global__ void solve_kernel(
    const float* __restrict__ P,    const float* __restrict__ Pd,   const float* __restrict__ Pdd,
    const float* __restrict__ lamv, const float* __restrict__ lamp, const float* __restrict__ lamr,
    const float* __restrict__ cinv, const float* __restrict__ cinp, const float* __restrict__ cinr,
    const float* __restrict__ beqv, const float* __restrict__ beqp, const float* __restrict__ beqr,
    const float* __restrict__ c0v,  const float* __restrict__ c0p,  const float* __restrict__ c0r,
    float* __restrict__ out, const float* __restrict__ ws)
{
    __shared__ __align__(16) float Pt[3][16][128];   // transposed: Pt[m][j][i]
    __shared__ float Ml[16][19];                     // M rows 0..15, cols 0..17 (pad 19)
    __shared__ float mq[16][17];                     // MQ = M*Q
    __shared__ float cs[12][17];                     // per-unit c (broadcast reads)
    __shared__ float res_st[ITERS][12];
    __shared__ float fix_st[ITERS][12];

    // ---- stage constants ----
#pragma unroll
    for (int m = 0; m < 3; ++m) {
        const float* src = (m == 0) ? P : (m == 1) ? Pd : Pdd;
        for (int f = threadIdx.x; f < 2048; f += 192) {
            int j = f >> 7, i = f & 127;
            Pt[m][j][i] = src[i*16 + j];
        }
    }
    for (int f = threadIdx.x; f < 288; f += 192) Ml[f / 18][f % 18] = ws[f];
    for (int f = threadIdx.x; f < 272; f += 192) mq[f / 17][f % 17] = ws[324 + f];
    __syncthreads();

    const int g  = threadIdx.x >> 4;   // group 0..11
    const int l  = threadIdx.x & 15;   // lane-in-group
    const int rl = g / 3;              // local row 0..3
    const int ch = g - rl * 3;         // channel 0..2
    const int row = blockIdx.x * 4 + rl;

    const float* lam_p = (ch == 0) ? lamv : (ch == 1) ? lamp : lamr;
    const float* cin_p = (ch == 0) ? cinv : (ch == 1) ? cinp : cinr;
    const float* beq_p = (ch == 0) ? beqv : (ch == 1) ? beqp : beqr;
    const float* c0_p  = (ch == 0) ? c0v  : (ch == 1) ? c0p  : c0r;

    // bounds per (ch, m)
    float bmax[3], bmin[3];
    bmax[0] = (ch == 0) ? 20.f : (ch == 1) ? 0.2f  : 0.25f;
    bmin[0] = (ch == 0) ? 12.f : (ch == 1) ? -0.2f : -0.25f;
    bmax[1] = (ch == 0) ? 3.f  : 0.25f;
    bmin[1] = (ch == 0) ? -3.f : -0.25f;
    bmax[2] = (ch == 0) ? 3.f  : 0.15f;
    bmin[2] = (ch == 0) ? -3.f : -0.15f;

    // ---- distributed per-unit state: lane l owns component l ----
    float c_l  = c0_p[row * 16 + l];
    float L_l  = lam_p[row * 16 + l] + cin_p[row * 16 + l];
    float pj_l;
    const float beq0 = beq_p[row * 2];
    const float beq1 = beq_p[row * 2 + 1];
    float uo[3][8];                    // lane's 8 constraint rows per derivative order

    cs[g][l] = c_l;

    // ---- init pass: uo, pjp0 -> reduce-scatter -> pj_l ----
    {
        float pjp[16];
#pragma unroll
        for (int j = 0; j < 16; ++j) pjp[j] = 0.f;

#pragma unroll
        for (int m = 0; m < 3; ++m) {
            float un[8];
#pragma unroll
            for (int k = 0; k < 8; ++k) un[k] = 0.f;
#pragma unroll 4
            for (int j = 0; j < 16; ++j) {
                float cj = cs[g][j];
                float4 p0 = *(const float4*)&Pt[m][j][4*l];
                float4 p1 = *(const float4*)&Pt[m][j][64 + 4*l];
                un[0] += cj*p0.x; un[1] += cj*p0.y; un[2] += cj*p0.z; un[3] += cj*p0.w;
                un[4] += cj*p1.x; un[5] += cj*p1.y; un[6] += cj*p1.z; un[7] += cj*p1.w;
            }
            float h[8];
#pragma unroll
            for (int k = 0; k < 8; ++k) {
                float x = un[k] - bmax[m];
                float rvp = fmaxf(x, 0.f);
                float y = un[k] - bmin[m];
                float rvm = fmaxf(-y, 0.f);
                h[k] = rvp - rvm;
                uo[m][k] = un[k];
            }
#pragma unroll 4
            for (int j = 0; j < 16; ++j) {
                float4 p0 = *(const float4*)&Pt[m][j][4*l];
                float4 p1 = *(const float4*)&Pt[m][j][64 + 4*l];
                pjp[j] += h[0]*p0.x + h[1]*p0.y + h[2]*p0.z + h[3]*p0.w
                        + h[4]*p1.x + h[5]*p1.y + h[6]*p1.z + h[7]*p1.w;
            }
        }
        pj_l = reduce_scatter16(pjp, l);
    }

    // ---- 15 ADMM iterations ----
    for (int t = 0; t < ITERS; ++t) {
        // KKT solve: sj = M*(L - pj) + MQ*c_old + eq-terms; lane l owns row l
        float r_l = L_l - pj_l;
        float sj = Ml[l][16] * beq0 + Ml[l][17] * beq1;
#pragma unroll
        for (int k = 0; k < 16; ++k) sj += Ml[l][k] * __shfl(r_l, k, 16);
#pragma unroll
        for (int k = 0; k < 16; ++k) sj += mq[l][k] * cs[g][k];   // old c

        float d = sj - c_l;
        float cdel2 = d * d;
        c_l = sj;
        cs[g][l] = c_l;                // overwrite AFTER the mq reads

        // fused Ax + projection + pjp accumulation (h stays in registers)
        float res2 = 0.f, ds2 = 0.f;
        float pjp[16];
#pragma unroll
        for (int j = 0; j < 16; ++j) pjp[j] = 0.f;

#pragma unroll
        for (int m = 0; m < 3; ++m) {
            float un[8];
#pragma unroll
            for (int k = 0; k < 8; ++k) un[k] = 0.f;
#pragma unroll 4
            for (int j = 0; j < 16; ++j) {
                float cj = cs[g][j];
                float4 p0 = *(const float4*)&Pt[m][j][4*l];
                float4 p1 = *(const float4*)&Pt[m][j][64 + 4*l];
                un[0] += cj*p0.x; un[1] += cj*p0.y; un[2] += cj*p0.z; un[3] += cj*p0.w;
                un[4] += cj*p1.x; un[5] += cj*p1.y; un[6] += cj*p1.z; un[7] += cj*p1.w;
            }
            float h[8];
#pragma unroll
            for (int k = 0; k < 8; ++k) {
                float x   = un[k] - bmax[m];
                float rvp = fmaxf(x, 0.f);        // relu(Ax - bmax)
                float spn = rvp - x;              // new s+
                float y   = un[k] - bmin[m];
                float smn = fmaxf(y, 0.f);        // new s-
                float rvm = smn - y;              // relu(bmin - Ax)
                res2 += rvp * rvp + rvm * rvm;
                h[k] = rvp - rvm;
                float xo  = uo[m][k] - bmax[m];
                float spo = fmaxf(-xo, 0.f);      // old s+
                float yo  = uo[m][k] - bmin[m];
                float smo = fmaxf(yo, 0.f);       // old s-
                float e1 = spn - spo;
                float e2 = smn - smo;
                ds2 += e1 * e1 + e2 * e2;
                uo[m][k] = un[k];
            }
#pragma unroll 4
            for (int j = 0; j < 16; ++j) {
                float4 p0 = *(const float4*)&Pt[m][j][4*l];
                float4 p1 = *(const float4*)&Pt[m][j][64 + 4*l];
                pjp[j] += h[0]*p0.x + h[1]*p0.y + h[2]*p0.z + h[3]*p0.w
                        + h[4]*p1.x + h[5]*p1.y + h[6]*p1.z + h[7]*p1.w;
            }
        }

        pj_l = reduce_scatter16(pjp, l);

        // butterfly 4 scalars across the 16 lanes (pj2 = ||lam_new-lam_old||^2)
        float pj2 = pj_l * pj_l;
#pragma unroll
        for (int s = 1; s < 16; s <<= 1) {
            res2  += __shfl_xor(res2,  s, 16);
            ds2   += __shfl_xor(ds2,   s, 16);
            cdel2 += __shfl_xor(cdel2, s, 16);
            pj2   += __shfl_xor(pj2,   s, 16);
        }

        L_l -= pj_l;

        if (l == 0) {
            res_st[t][g] = sqrtf(res2);
            fix_st[t][g] = sqrtf(pj2) + sqrtf(ds2) + sqrtf(cdel2);
        }
    }

    // ---- outputs ----
    out[ch * (BATCH * NVARS) + row * 16 + l] = c_l;   // lane l owns c[l]

    __syncthreads();
    const int t2 = threadIdx.x;
    if (t2 < 60) {
        int it = t2 % 15, r2 = t2 / 15, gb = r2 * 3;
        out[OUT_PST + it * BATCH + blockIdx.x * 4 + r2] =
            res_st[it][gb] + res_st[it][gb + 1] + res_st[it][gb + 2];
    } else if (t2 < 120) {
        int t3 = t2 - 60;
        int it = t3 % 15, r2 = t3 / 15, gb = r2 * 3;
        out[OUT_FST + it * BATCH + blockIdx.x * 4 + r2] =
            fix_st[it][gb] + fix_st[it][gb + 1] + fix_st[it][gb + 2];
    } else if (t2 < 124) {
        int r2 = t2 - 120, gb = r2 * 3;
        float s = 0.f;
        for (int it = 0; it < ITERS; ++it)
            s += fix_st[it][gb] + fix_st[it][gb + 1] + fix_st[it][gb + 2];
        out[OUT_ACCF + blockIdx.x * 4 + r2] = s * (1.f / 15.f);
    } else if (t2 < 128) {
        int r2 = t2 - 124, gb = r2 * 3;
        float s = 0.f;
        for (int it = 0; it < ITERS; ++it)
            s += res_st[it][gb] + res_st[it][gb + 1] + res_st[it][gb + 2];
        out[OUT_ACCP + blockIdx.x * 4 + r2] = s * (1.f / 15.f);
    }
}

extern "C" void kernel_launch(void* const* d_in, const int* in_sizes, int n_in,
                              void* d_out, int out_size, void* d_ws, size_t ws_size,
                              hipStream_t stream)
{
    const float* P    = (const float*)d_in[0];
    const float* Pdm  = (const float*)d_in[1];
    const float* Pddm = (const float*)d_in[2];
    const float* lamv = (const float*)d_in[3];
    const float* lamp = (const float*)d_in[4];
    const float* lamr = (const float*)d_in[5];
    const float* cinv = (const float*)d_in[6];
    const float* cinp = (const float*)d_in[7];
    const float* cinr = (const float*)d_in[8];
    const float* beqv = (const float*)d_in[9];
    const float* beqp = (const float*)d_in[10];
    const float* beqr = (const float*)d_in[11];
    const float* c0v  = (const float*)d_in[12];
    const float* c0p  = (const float*)d_in[13];
    const float* c0r  = (const float*)d_in[14];
    float* ws = (float*)d_ws;

    prep_kernel<<<1, 648, 0, stream>>>(P, Pdm, Pddm, ws);
    solve_kernel<<<2048, 192, 0, stream>>>(P, Pdm, Pddm,
        lamv, lamp, lamr, cinv, cinp, cinr,
        beqv, beqp, beqr, c0v, c0p, c0r,
        (float*)d_out, ws);
}